// Round 2
// baseline (235.423 us; speedup 1.0000x reference)
//
#include <hip/hip_runtime.h>
#include <math.h>

#define CCH 256
#define HH  96
#define WW  96
#define HW  9216      // H*W
#define CW  24576     // C*W (columns of the [96, 24576] reshape)
#define TWO_PI 6.28318530717958647692f

// ---------------- Kernel 1: fused |x| min/max + 16-coefficient DFT band-pass ----------------
// One block per channel, 256 threads. Stages |x| in LDS (one global read),
// computes min/max, the 16 kept DFT coefficients (ky,kx in {-2,-1,0,1} after
// un-fftshift), and synthesizes FQ[y,x] = |(1/9216) sum F e^{+i phase}|.
__global__ __launch_bounds__(256) void k_freq(const float* __restrict__ x,
                                              float* __restrict__ FQ) {
    __shared__ float qa[HW];        // 36 KB: |x| for this channel
    __shared__ float cs[96][2];     // cos/sin(2π t/96)
    __shared__ float rlo[256], rhi[256];
    __shared__ float Gs[4][96][2];  // per-column y-DFT, k index 0..3 -> k=-2..+1
    __shared__ float Fs[4][4][2];   // the 16 coefficients
    __shared__ float Ps[4][96][2];  // per-column x-phase partial products
    __shared__ float s_mn, s_pt;

    int c = blockIdx.x;
    int t = threadIdx.x;
    const float* xp = x + c * HW;

    float lo = 1e30f, hi = -1e30f;
    for (int i = t; i < HW; i += 256) {
        float a = fabsf(xp[i]);
        qa[i] = a;
        lo = fminf(lo, a);
        hi = fmaxf(hi, a);
    }
    if (t < 96) {
        float ang = TWO_PI * (float)t / 96.0f;
        cs[t][0] = cosf(ang);
        cs[t][1] = sinf(ang);
    }
    rlo[t] = lo; rhi[t] = hi;
    __syncthreads();
    for (int s = 128; s > 0; s >>= 1) {
        if (t < s) {
            rlo[t] = fminf(rlo[t], rlo[t + s]);
            rhi[t] = fmaxf(rhi[t], rhi[t + s]);
        }
        __syncthreads();
    }
    if (t == 0) { s_mn = rlo[0]; s_pt = rhi[0] - rlo[0]; }
    __syncthreads();

    float m0 = s_mn, pt = s_pt;

    // Phase A: G[k, x=t] = sum_y q[y,t] * e^{-2πi k y/96}, k=-2..0 (+1 = conj(-1))
    if (t < 96) {
        float g0r = 0.f, g0i = 0.f, g1r = 0.f, g1i = 0.f, g2 = 0.f;
        for (int y = 0; y < 96; ++y) {
            float a = qa[y * 96 + t];
            float q = floorf(255.0f * (a - m0) / pt);
            float c1 = cs[y][0], s1 = cs[y][1];
            float c2 = c1 * c1 - s1 * s1, s2 = 2.0f * c1 * s1;
            g0r += q * c2; g0i += q * s2;   // k=-2: e^{+2iθ}
            g1r += q * c1; g1i += q * s1;   // k=-1: e^{+iθ}
            g2  += q;                       // k=0
        }
        Gs[0][t][0] = g0r; Gs[0][t][1] = g0i;
        Gs[1][t][0] = g1r; Gs[1][t][1] = g1i;
        Gs[2][t][0] = g2;  Gs[2][t][1] = 0.f;
        Gs[3][t][0] = g1r; Gs[3][t][1] = -g1i;
    }
    __syncthreads();

    // Phase A2: F[ky,kx] = sum_x G[ky,x] * e^{-2πi (kx-2) x/96}
    if (t < 16) {
        int ky = t >> 2, kx = t & 3;
        float fr = 0.f, fi = 0.f;
        for (int xx = 0; xx < 96; ++xx) {
            float c1 = cs[xx][0], s1 = cs[xx][1];
            float er, ei;
            if (kx == 0)      { er = c1 * c1 - s1 * s1; ei = 2.0f * c1 * s1; }
            else if (kx == 1) { er = c1; ei = s1;  }
            else if (kx == 2) { er = 1.f; ei = 0.f; }
            else              { er = c1; ei = -s1; }
            float gr = Gs[ky][xx][0], gi = Gs[ky][xx][1];
            fr += gr * er - gi * ei;
            fi += gr * ei + gi * er;
        }
        Fs[ky][kx][0] = fr; Fs[ky][kx][1] = fi;
    }
    __syncthreads();

    // Phase P: per-column x-phase products P[ky](x) = sum_kx F[ky,kx] T[kx](x)
    if (t < 96) {
        float c1 = cs[t][0], s1 = cs[t][1];
        float c2 = c1 * c1 - s1 * s1, s2 = 2.0f * c1 * s1;
        float Tr[4] = { c2, c1, 1.f, c1 };
        float Ti[4] = { -s2, -s1, 0.f, s1 };
        #pragma unroll
        for (int ky = 0; ky < 4; ++ky) {
            float pr = 0.f, pi = 0.f;
            #pragma unroll
            for (int kx = 0; kx < 4; ++kx) {
                float fr = Fs[ky][kx][0], fi = Fs[ky][kx][1];
                pr += fr * Tr[kx] - fi * Ti[kx];
                pi += fr * Ti[kx] + fi * Tr[kx];
            }
            Ps[ky][t][0] = pr; Ps[ky][t][1] = pi;
        }
    }
    __syncthreads();

    // Phase B: synthesis over all 9216 pixels with all 256 threads
    float* outp = FQ + c * HW;
    const float inv = 1.0f / 9216.0f;
    for (int i = t; i < HW; i += 256) {
        int y = i / 96;
        int xx = i - y * 96;
        float cy = cs[y][0], sy = cs[y][1];
        float cy2 = cy * cy - sy * sy, sy2 = 2.0f * cy * sy;
        float p0r = Ps[0][xx][0], p0i = Ps[0][xx][1];
        float p1r = Ps[1][xx][0], p1i = Ps[1][xx][1];
        float p2r = Ps[2][xx][0], p2i = Ps[2][xx][1];
        float p3r = Ps[3][xx][0], p3i = Ps[3][xx][1];
        float ar =  p0r * cy2 + p0i * sy2
                 +  p1r * cy  + p1i * sy
                 +  p2r
                 +  p3r * cy  - p3i * sy;
        float ai = -p0r * sy2 + p0i * cy2
                 -  p1r * sy  + p1i * cy
                 +  p2i
                 +  p3r * sy  + p3i * cy;
        outp[i] = sqrtf(ar * ar + ai * ai) * inv;
    }
}

// ---------------- GEMM: out[o,p] = sum_c W[o,c] X[c,p] + b[o] ----------------
// grid (72, 16): 128 pixels per block.x (128 threads), 16 output channels per
// block.y. gridDim.x = 72 ≡ 0 (mod 8) so all 16 o-blocks of one pixel-block
// share bid%8 -> same XCD -> X slice (128 KB) is read from L3 once and served
// from that XCD's L2 for the other 15 blocks.
// Weights are wave-uniform -> s_load into SGPRs; inner loop is pure v_fmac.
template<bool APPLY_MASK>
__global__ __launch_bounds__(128) void k_gemm(const float* __restrict__ X,
                                              const float* __restrict__ Wm,
                                              const float* __restrict__ bias,
                                              const float* __restrict__ mask,
                                              float* __restrict__ out) {
    int p  = blockIdx.x * 128 + threadIdx.x;
    int ob = blockIdx.y * 16;

    float acc[16];
    #pragma unroll
    for (int j = 0; j < 16; ++j) acc[j] = 0.f;

    #pragma unroll 2
    for (int c0 = 0; c0 < 256; c0 += 4) {
        float w[16][4];   // wave-uniform -> SGPRs via s_load_dwordx4
        #pragma unroll
        for (int j = 0; j < 16; ++j)
            #pragma unroll
            for (int cc = 0; cc < 4; ++cc)
                w[j][cc] = Wm[(ob + j) * 256 + c0 + cc];
        float xv[4];
        #pragma unroll
        for (int cc = 0; cc < 4; ++cc)
            xv[cc] = X[(c0 + cc) * HW + p];
        #pragma unroll
        for (int cc = 0; cc < 4; ++cc)
            #pragma unroll
            for (int j = 0; j < 16; ++j)
                acc[j] += w[j][cc] * xv[cc];
    }

    #pragma unroll
    for (int j = 0; j < 16; ++j) {
        int o = ob + j;
        float v = acc[j] + bias[o];
        if (APPLY_MASK) {
            // mask index = (o*9216 + p) mod 24576 = ((o&7)*9216 + p) mod 24576
            int k = (o & 7) * HW + p;
            if (k >= CW) k -= CW;
            if (k >= CW) k -= CW;
            v = v * (1.0f + mask[k]);
        }
        out[o * HW + p] = v;
    }
}

// ---------------- FQmax[k] = max_{r<96} Q_flat[r*24576 + k] ----------------
__global__ __launch_bounds__(256) void k_colmax(const float* __restrict__ Q,
                                                float* __restrict__ mx) {
    int k = blockIdx.x * 256 + threadIdx.x;
    float m = -1e30f;
    #pragma unroll 4
    for (int r = 0; r < 96; ++r)
        m = fmaxf(m, Q[r * CW + k]);
    mx[k] = m;
}

extern "C" void kernel_launch(void* const* d_in, const int* in_sizes, int n_in,
                              void* d_out, int out_size, void* d_ws, size_t ws_size,
                              hipStream_t stream) {
    const float* fuse = (const float*)d_in[0];
    const float* Wq   = (const float*)d_in[1];
    const float* bq   = (const float*)d_in[2];
    // d_in[3]=Wk, d_in[4]=bk dead for B=1 (softmax over batch axis of size 1 == 1)
    const float* Wv   = (const float*)d_in[5];
    const float* bv   = (const float*)d_in[6];
    float* out = (float*)d_out;

    float* ws    = (float*)d_ws;
    float* FQmax = ws;            // 24576
    float* FQ    = ws + CW;       // 2359296
    float* Q     = out;           // d_out doubles as Q scratch (exactly 2359296 floats)

    k_freq<<<256, 256, 0, stream>>>(fuse, FQ);
    k_gemm<false><<<dim3(72, 16), 128, 0, stream>>>(FQ, Wq, bq, nullptr, Q);
    k_colmax<<<96, 256, 0, stream>>>(Q, FQmax);
    k_gemm<true><<<dim3(72, 16), 128, 0, stream>>>(fuse, Wv, bv, FQmax, out);
}

// Round 3
// 149.188 us; speedup vs baseline: 1.5780x; 1.5780x over previous
//
#include <hip/hip_runtime.h>
#include <math.h>

#define CCH 256
#define HW  9216
#define CW  24576
#define TWO_PI 6.28318530717958647692f

typedef __attribute__((ext_vector_type(8))) short short8;
typedef __attribute__((ext_vector_type(4))) float f32x4;

__device__ inline unsigned short f2bf(float f) {
    unsigned u = __float_as_uint(f);
    unsigned r = (u + 0x7FFFu + ((u >> 16) & 1u)) >> 16;   // RNE
    return (unsigned short)r;
}

// ---------------- K1: per-channel min/max + 16 DFT coefficients ----------------
// Kept freqs (un-fftshifted): ky,kx in {-2,-1,0,1}. Writes Fg[c*32 + 2*(ky*4+kx) + {re,im}].
__global__ __launch_bounds__(256) void k_stats(const float* __restrict__ x,
                                               float* __restrict__ Fg) {
    __shared__ float cs[96][2];
    __shared__ float rlo[256], rhi[256];
    __shared__ float Gp[2][96][5];
    __shared__ float Gs[96][6];
    __shared__ float s_mn, s_pt;
    int c = blockIdx.x, t = threadIdx.x;
    const float* xp = x + c * HW;
    if (t < 96) { float a = TWO_PI * (float)t / 96.0f; cs[t][0] = cosf(a); cs[t][1] = sinf(a); }
    float lo = 1e30f, hi = -1e30f;
    for (int i = t; i < HW; i += 256) { float a = fabsf(xp[i]); lo = fminf(lo, a); hi = fmaxf(hi, a); }
    rlo[t] = lo; rhi[t] = hi;
    __syncthreads();
    for (int s = 128; s > 0; s >>= 1) {
        if (t < s) { rlo[t] = fminf(rlo[t], rlo[t + s]); rhi[t] = fmaxf(rhi[t], rhi[t + s]); }
        __syncthreads();
    }
    if (t == 0) { s_mn = rlo[0]; s_pt = rhi[0] - rlo[0]; }
    __syncthreads();
    float m0 = s_mn, pt = s_pt;

    // Column DFTs over y, split in two halves for parallelism
    if (t < 192) {
        int xx = t % 96, h = t / 96;
        float g0r = 0, g0i = 0, g1r = 0, g1i = 0, g2 = 0;
        for (int y = h * 48; y < h * 48 + 48; ++y) {
            float a = fabsf(xp[y * 96 + xx]);
            float q = floorf(255.0f * (a - m0) / pt);
            float c1 = cs[y][0], s1 = cs[y][1];
            float c2 = c1 * c1 - s1 * s1, s2 = 2.0f * c1 * s1;
            g0r += q * c2; g0i += q * s2;   // k=-2: e^{+2iθ}
            g1r += q * c1; g1i += q * s1;   // k=-1: e^{+iθ}
            g2  += q;                       // k=0
        }
        Gp[h][xx][0] = g0r; Gp[h][xx][1] = g0i; Gp[h][xx][2] = g1r; Gp[h][xx][3] = g1i; Gp[h][xx][4] = g2;
    }
    __syncthreads();
    if (t < 96) {
        #pragma unroll
        for (int j = 0; j < 5; ++j) Gs[t][j] = Gp[0][t][j] + Gp[1][t][j];
        Gs[t][5] = 0.f;
    }
    __syncthreads();
    if (t < 16) {
        int ky = t >> 2, kx = t & 3;
        float fr = 0, fi = 0;
        #pragma unroll 4
        for (int xx = 0; xx < 96; ++xx) {
            float c1 = cs[xx][0], s1 = cs[xx][1];
            float er, ei;
            if (kx == 0)      { er = c1 * c1 - s1 * s1; ei = 2.0f * c1 * s1; }
            else if (kx == 1) { er = c1; ei = s1; }
            else if (kx == 2) { er = 1.f; ei = 0.f; }
            else              { er = c1; ei = -s1; }
            float gr, gi;
            if (ky == 0)      { gr = Gs[xx][0]; gi = Gs[xx][1]; }
            else if (ky == 1) { gr = Gs[xx][2]; gi = Gs[xx][3]; }
            else if (ky == 2) { gr = Gs[xx][4]; gi = 0.f; }
            else              { gr = Gs[xx][2]; gi = -Gs[xx][3]; }
            fr += gr * er - gi * ei;
            fi += gr * ei + gi * er;
        }
        Fg[c * 32 + 2 * t]     = fr;
        Fg[c * 32 + 2 * t + 1] = fi;
    }
}

// ---------------- K2: synthesis -> FQ bf16 in GEMM tile order [ptile][kc][n] ----------------
// block = (x=blockIdx.x, y-range 32*blockIdx.y), thread = channel c
__global__ __launch_bounds__(256) void k_synth(const float* __restrict__ Fg,
                                               unsigned short* __restrict__ XTq) {
    int c = threadIdx.x;
    int bx = blockIdx.x;
    int y0 = blockIdx.y * 32;
    float Fr[4][4], Fi[4][4];
    #pragma unroll
    for (int k = 0; k < 16; ++k) {
        Fr[k >> 2][k & 3] = Fg[c * 32 + 2 * k];
        Fi[k >> 2][k & 3] = Fg[c * 32 + 2 * k + 1];
    }
    float ax = TWO_PI * (float)bx / 96.0f;
    float cx = cosf(ax), sx = sinf(ax);
    float cx2 = cx * cx - sx * sx, sx2 = 2.0f * cx * sx;
    float Txr[4] = { cx2, cx, 1.f, cx };
    float Txi[4] = { -sx2, -sx, 0.f, sx };
    float Pr[4], Pi[4];
    #pragma unroll
    for (int ky = 0; ky < 4; ++ky) {
        float pr = 0, pi = 0;
        #pragma unroll
        for (int kx = 0; kx < 4; ++kx) {
            pr += Fr[ky][kx] * Txr[kx] - Fi[ky][kx] * Txi[kx];
            pi += Fr[ky][kx] * Txi[kx] + Fi[ky][kx] * Txr[kx];
        }
        Pr[ky] = pr; Pi[ky] = pi;
    }
    const float inv = 1.0f / 9216.0f;
    for (int y = y0; y < y0 + 32; ++y) {
        float ay = TWO_PI * (float)y / 96.0f;
        float cy = cosf(ay), sy = sinf(ay);
        float cy2 = cy * cy - sy * sy, sy2 = 2.0f * cy * sy;
        float ar =  Pr[0] * cy2 + Pi[0] * sy2 + Pr[1] * cy + Pi[1] * sy + Pr[2] + Pr[3] * cy - Pi[3] * sy;
        float ai = -Pr[0] * sy2 + Pi[0] * cy2 - Pr[1] * sy + Pi[1] * cy + Pi[2] + Pr[3] * sy + Pi[3] * cy;
        float v = sqrtf(ar * ar + ai * ai) * inv;
        int p = y * 96 + bx;
        XTq[(size_t)(((p >> 6) * 2048) + ((c >> 3) * 64) + (p & 63)) * 8 + (c & 7)] = f2bf(v);
    }
}

// ---------------- K3: fuse -> bf16 transposed tiles [ptile][kc=c/8][n=p%64] ----------------
__global__ __launch_bounds__(256) void k_transp(const float* __restrict__ x,
                                                unsigned short* __restrict__ XTv) {
    __shared__ unsigned short lt[64][66];
    int ptile = blockIdx.x, ct = blockIdx.y;
    int t = threadIdx.x;
    int tx = t & 63, tw = t >> 6;
    int p0 = ptile * 64, c0 = ct * 64;
    #pragma unroll
    for (int i = 0; i < 16; ++i) {
        int row = tw * 16 + i;
        lt[row][tx] = f2bf(x[(size_t)(c0 + row) * HW + p0 + tx]);
    }
    __syncthreads();
    short8* dst = (short8*)XTv;
    #pragma unroll
    for (int ch = 0; ch < 2; ++ch) {
        int lc = ch * 256 + t;
        int kcg = lc >> 6, n = lc & 63;
        short8 v;
        #pragma unroll
        for (int e = 0; e < 8; ++e) v[e] = (short)lt[kcg * 8 + e][n];
        dst[ptile * 2048 + (ct * 8 + kcg) * 64 + n] = v;
    }
}

// ---------------- Kw: weights -> bf16 tiles [ot][kc][m] ----------------
__global__ __launch_bounds__(256) void k_wconv(const float* __restrict__ Wq,
                                               const float* __restrict__ Wv,
                                               short8* __restrict__ Wqt,
                                               short8* __restrict__ Wvt) {
    int cidx = blockIdx.x * 256 + threadIdx.x;          // 0..8191
    const float* src = blockIdx.y ? Wv : Wq;
    short8* dst = blockIdx.y ? Wvt : Wqt;
    int ot = cidx >> 11, kc = (cidx >> 6) & 31, m = cidx & 63;
    const float* s = src + (ot * 64 + m) * 256 + kc * 8;
    short8 v;
    #pragma unroll
    for (int e = 0; e < 8; ++e) v[e] = (short)f2bf(s[e]);
    dst[cidx] = v;
}

// ---------------- MFMA GEMM 64x64 tile, K=256 one-shot in LDS ----------------
// EPI=1: Q-GEMM, epilogue = column-max into FQm (monotone-uint atomicMax), Q never stored.
// EPI=2: V-GEMM, epilogue = out = (V+b) * (1 + decode(FQm[k])).
template<int EPI>
__global__ __launch_bounds__(256) void k_gemm(const short8* __restrict__ Wt,
                                              const short8* __restrict__ Xt,
                                              const float* __restrict__ bias,
                                              unsigned* __restrict__ FQm,
                                              float* __restrict__ out) {
    __shared__ short8 As[2048];   // 32 KB  [kc][m]
    __shared__ short8 Bs[2048];   // 32 KB  [kc][n]
    int tid = threadIdx.x;
    int pt_ = blockIdx.x, ot = blockIdx.y;
    const short8* wsrc = Wt + ot * 2048;
    const short8* xsrc = Xt + pt_ * 2048;
    #pragma unroll
    for (int i = 0; i < 8; ++i) As[i * 256 + tid] = wsrc[i * 256 + tid];
    #pragma unroll
    for (int i = 0; i < 8; ++i) Bs[i * 256 + tid] = xsrc[i * 256 + tid];
    __syncthreads();

    int l = tid & 63, w = tid >> 6;
    int wr = w >> 1, wc = w & 1;           // wave tile: rows wr*32, cols wc*32
    int l15 = l & 15, quad = l >> 4;
    f32x4 acc[2][2] = {};
    int abase = wr * 32 + l15;
    int bbase = wc * 32 + l15;
    #pragma unroll
    for (int s = 0; s < 8; ++s) {
        int kc = s * 4 + quad;             // lane's 16B chunk covers k = s*32 + quad*8 + j
        short8 a0 = As[kc * 64 + abase];
        short8 a1 = As[kc * 64 + abase + 16];
        short8 b0 = Bs[kc * 64 + bbase];
        short8 b1 = Bs[kc * 64 + bbase + 16];
        acc[0][0] = __builtin_amdgcn_mfma_f32_16x16x32_bf16(a0, b0, acc[0][0], 0, 0, 0);
        acc[0][1] = __builtin_amdgcn_mfma_f32_16x16x32_bf16(a0, b1, acc[0][1], 0, 0, 0);
        acc[1][0] = __builtin_amdgcn_mfma_f32_16x16x32_bf16(a1, b0, acc[1][0], 0, 0, 0);
        acc[1][1] = __builtin_amdgcn_mfma_f32_16x16x32_bf16(a1, b1, acc[1][1], 0, 0, 0);
    }

    // C/D layout: col = lane&15, row = quad*4 + reg  (m89/m91 verified)
    if (EPI == 1) {
        #pragma unroll
        for (int ni = 0; ni < 2; ++ni) {
            #pragma unroll
            for (int r = 0; r < 4; ++r) {
                int o_lo = ot * 64 + wr * 32 + quad * 4 + r;   // mi=0 row; mi=1 is +16
                float v = fmaxf(acc[0][ni][r] + bias[o_lo], acc[1][ni][r] + bias[o_lo + 16]);
                v = fmaxf(v, __shfl_xor(v, 32, 64));            // quad0<->2, 1<->3 share k
                if (quad < 2) {
                    int p = pt_ * 64 + wc * 32 + ni * 16 + l15;
                    int k = ((quad * 4 + r) & 7) * HW + p;      // (o&7) since o0,mi*16 ≡ 0 mod 8
                    if (k >= CW) k -= CW;
                    if (k >= CW) k -= CW;
                    unsigned u = __float_as_uint(v);
                    unsigned key = (u & 0x80000000u) ? ~u : (u | 0x80000000u);
                    atomicMax(&FQm[k], key);
                }
            }
        }
    } else {
        #pragma unroll
        for (int mi = 0; mi < 2; ++mi) {
            #pragma unroll
            for (int ni = 0; ni < 2; ++ni) {
                #pragma unroll
                for (int r = 0; r < 4; ++r) {
                    int o = ot * 64 + wr * 32 + mi * 16 + quad * 4 + r;
                    int p = pt_ * 64 + wc * 32 + ni * 16 + l15;
                    int k = ((quad * 4 + r) & 7) * HW + p;
                    if (k >= CW) k -= CW;
                    if (k >= CW) k -= CW;
                    unsigned key = FQm[k];
                    unsigned ub = (key & 0x80000000u) ? (key ^ 0x80000000u) : ~key;
                    float m = __uint_as_float(ub);
                    float v = acc[mi][ni][r] + bias[o];
                    out[(size_t)o * HW + p] = v * (1.0f + m);
                }
            }
        }
    }
}

extern "C" void kernel_launch(void* const* d_in, const int* in_sizes, int n_in,
                              void* d_out, int out_size, void* d_ws, size_t ws_size,
                              hipStream_t stream) {
    const float* fuse = (const float*)d_in[0];
    const float* Wq   = (const float*)d_in[1];
    const float* bq   = (const float*)d_in[2];
    // d_in[3]=Wk, d_in[4]=bk dead for B=1 (softmax over batch axis of size 1 == 1)
    const float* Wv   = (const float*)d_in[5];
    const float* bv   = (const float*)d_in[6];
    float* out = (float*)d_out;

    char* ws = (char*)d_ws;
    unsigned*       FQm = (unsigned*)(ws);                  //  98304 B  (24576 u32)
    float*          Fg  = (float*)(ws + 98304);             //  32768 B  (256 x 32 f32)
    short8*         Wqt = (short8*)(ws + 131072);           // 131072 B
    short8*         Wvt = (short8*)(ws + 262144);           // 131072 B
    unsigned short* XTq = (unsigned short*)(ws + 393216);   // 4718592 B (FQ bf16 tiles)
    unsigned short* XTv = (unsigned short*)(ws + 5111808);  // 4718592 B (fuse bf16 tiles)

    hipMemsetAsync(FQm, 0, 24576 * sizeof(unsigned), stream);
    k_wconv<<<dim3(32, 2), 256, 0, stream>>>(Wq, Wv, Wqt, Wvt);
    k_stats<<<256, 256, 0, stream>>>(fuse, Fg);
    k_synth<<<dim3(96, 3), 256, 0, stream>>>(Fg, XTq);
    k_transp<<<dim3(144, 4), 256, 0, stream>>>(fuse, XTv);
    k_gemm<1><<<dim3(144, 4), 256, 0, stream>>>(Wqt, (const short8*)XTq, bq, FQm, nullptr);
    k_gemm<2><<<dim3(144, 4), 256, 0, stream>>>(Wvt, (const short8*)XTv, bv, FQm, out);
}

// Round 4
// 126.688 us; speedup vs baseline: 1.8583x; 1.1776x over previous
//
#include <hip/hip_runtime.h>
#include <math.h>

#define CCH 256
#define HW  9216
#define CW  24576
#define TWO_PI 6.28318530717958647692f

typedef __attribute__((ext_vector_type(8))) short short8;
typedef __attribute__((ext_vector_type(4))) float f32x4;

__device__ inline unsigned short f2bf(float f) {
    unsigned u = __float_as_uint(f);
    unsigned r = (u + 0x7FFFu + ((u >> 16) & 1u)) >> 16;   // RNE
    return (unsigned short)r;
}

// ---------------- K0: per-channel min/max of |x|, 8 blocks per channel ----------------
// MnMx[c]       = monotone-u32 max(|x|)   (raw bits, |x|>=0)
// MnMx[256 + c] = monotone-u32 encoded min: max(~bits)
__global__ __launch_bounds__(256) void k_minmax(const float* __restrict__ x,
                                                unsigned* __restrict__ MnMx) {
    int b = blockIdx.x;            // 0..2047
    int c = b >> 3, s = b & 7;
    const float* p = x + c * HW + s * 1152;
    int t = threadIdx.x;
    float lo = 1e30f, hi = 0.f;
    for (int i = t; i < 1152; i += 256) {
        float a = fabsf(p[i]);
        lo = fminf(lo, a);
        hi = fmaxf(hi, a);
    }
    #pragma unroll
    for (int d = 32; d; d >>= 1) {
        lo = fminf(lo, __shfl_xor(lo, d, 64));
        hi = fmaxf(hi, __shfl_xor(hi, d, 64));
    }
    __shared__ float slo[4], shi[4];
    int w = t >> 6;
    if ((t & 63) == 0) { slo[w] = lo; shi[w] = hi; }
    __syncthreads();
    if (t == 0) {
        lo = fminf(fminf(slo[0], slo[1]), fminf(slo[2], slo[3]));
        hi = fmaxf(fmaxf(shi[0], shi[1]), fmaxf(shi[2], shi[3]));
        atomicMax(&MnMx[c], __float_as_uint(hi));
        atomicMax(&MnMx[256 + c], ~__float_as_uint(lo));
    }
}

// ---------------- K1: 16 DFT coefficients per channel (min/max precomputed) ----------------
// Kept freqs (un-fftshifted): ky,kx in {-2,-1,0,1}. Writes Fg[c*32 + 2*(ky*4+kx) + {re,im}].
__global__ __launch_bounds__(768) void k_dft(const float* __restrict__ x,
                                             const unsigned* __restrict__ MnMx,
                                             float* __restrict__ Fg) {
    __shared__ float cs[96][2];
    __shared__ float Gp[8][96][5];   // per-y-chunk partial column DFTs
    __shared__ float Gs[96][6];
    int c = blockIdx.x, t = threadIdx.x;
    if (t < 96) { float a = TWO_PI * (float)t / 96.0f; cs[t][0] = cosf(a); cs[t][1] = sinf(a); }
    float mxv = __uint_as_float(MnMx[c]);
    float mn  = __uint_as_float(~MnMx[256 + c]);
    float ptp = mxv - mn;
    __syncthreads();

    // Phase A: thread (xx = t%96, h = t/96) sums 12 rows of the column DFT
    {
        int xx = t % 96, h = t / 96;
        const float* xp = x + c * HW;
        float g0r = 0, g0i = 0, g1r = 0, g1i = 0, g2 = 0;
        for (int y = h * 12; y < h * 12 + 12; ++y) {
            float a = fabsf(xp[y * 96 + xx]);
            float q = floorf(255.0f * (a - mn) / ptp);
            float c1 = cs[y][0], s1 = cs[y][1];
            float c2 = c1 * c1 - s1 * s1, s2 = 2.0f * c1 * s1;
            g0r += q * c2; g0i += q * s2;   // k=-2: e^{+2iθ}
            g1r += q * c1; g1i += q * s1;   // k=-1: e^{+iθ}
            g2  += q;                       // k=0
        }
        Gp[h][xx][0] = g0r; Gp[h][xx][1] = g0i;
        Gp[h][xx][2] = g1r; Gp[h][xx][3] = g1i;
        Gp[h][xx][4] = g2;
    }
    __syncthreads();
    if (t < 96) {
        #pragma unroll
        for (int j = 0; j < 5; ++j) {
            float s = 0.f;
            #pragma unroll
            for (int h = 0; h < 8; ++h) s += Gp[h][t][j];
            Gs[t][j] = s;
        }
        Gs[t][5] = 0.f;
    }
    __syncthreads();
    // Phase A2: 64 threads = 16 coefs x 4 column-quarters, shfl combine
    if (t < 64) {
        int coef = t >> 2, qq = t & 3;
        int ky = coef >> 2, kx = coef & 3;
        float fr = 0, fi = 0;
        for (int xx = qq * 24; xx < qq * 24 + 24; ++xx) {
            float c1 = cs[xx][0], s1 = cs[xx][1];
            float er, ei;
            if (kx == 0)      { er = c1 * c1 - s1 * s1; ei = 2.0f * c1 * s1; }
            else if (kx == 1) { er = c1; ei = s1; }
            else if (kx == 2) { er = 1.f; ei = 0.f; }
            else              { er = c1; ei = -s1; }
            float gr, gi;
            if (ky == 0)      { gr = Gs[xx][0]; gi = Gs[xx][1]; }
            else if (ky == 1) { gr = Gs[xx][2]; gi = Gs[xx][3]; }
            else if (ky == 2) { gr = Gs[xx][4]; gi = 0.f; }
            else              { gr = Gs[xx][2]; gi = -Gs[xx][3]; }
            fr += gr * er - gi * ei;
            fi += gr * ei + gi * er;
        }
        fr += __shfl_xor(fr, 1, 64); fr += __shfl_xor(fr, 2, 64);
        fi += __shfl_xor(fi, 1, 64); fi += __shfl_xor(fi, 2, 64);
        if (qq == 0) {
            Fg[c * 32 + 2 * coef]     = fr;
            Fg[c * 32 + 2 * coef + 1] = fi;
        }
    }
}

// ---------------- K2: synthesis -> FQ bf16 in GEMM tile order [ptile][kc][n] ----------------
__global__ __launch_bounds__(256) void k_synth(const float* __restrict__ Fg,
                                               unsigned short* __restrict__ XTq) {
    int c = threadIdx.x;
    int bx = blockIdx.x;
    int y0 = blockIdx.y * 32;
    float Fr[4][4], Fi[4][4];
    #pragma unroll
    for (int k = 0; k < 16; ++k) {
        Fr[k >> 2][k & 3] = Fg[c * 32 + 2 * k];
        Fi[k >> 2][k & 3] = Fg[c * 32 + 2 * k + 1];
    }
    float ax = TWO_PI * (float)bx / 96.0f;
    float cx = cosf(ax), sx = sinf(ax);
    float cx2 = cx * cx - sx * sx, sx2 = 2.0f * cx * sx;
    float Txr[4] = { cx2, cx, 1.f, cx };
    float Txi[4] = { -sx2, -sx, 0.f, sx };
    float Pr[4], Pi[4];
    #pragma unroll
    for (int ky = 0; ky < 4; ++ky) {
        float pr = 0, pi = 0;
        #pragma unroll
        for (int kx = 0; kx < 4; ++kx) {
            pr += Fr[ky][kx] * Txr[kx] - Fi[ky][kx] * Txi[kx];
            pi += Fr[ky][kx] * Txi[kx] + Fi[ky][kx] * Txr[kx];
        }
        Pr[ky] = pr; Pi[ky] = pi;
    }
    const float inv = 1.0f / 9216.0f;
    for (int y = y0; y < y0 + 32; ++y) {
        float ay = TWO_PI * (float)y / 96.0f;
        float cy = cosf(ay), sy = sinf(ay);
        float cy2 = cy * cy - sy * sy, sy2 = 2.0f * cy * sy;
        float ar =  Pr[0] * cy2 + Pi[0] * sy2 + Pr[1] * cy + Pi[1] * sy + Pr[2] + Pr[3] * cy - Pi[3] * sy;
        float ai = -Pr[0] * sy2 + Pi[0] * cy2 - Pr[1] * sy + Pi[1] * cy + Pi[2] + Pr[3] * sy + Pi[3] * cy;
        float v = sqrtf(ar * ar + ai * ai) * inv;
        int p = y * 96 + bx;
        XTq[(size_t)(((p >> 6) * 2048) + ((c >> 3) * 64) + (p & 63)) * 8 + (c & 7)] = f2bf(v);
    }
}

// ---------------- K3: fuse -> bf16 transposed tiles [ptile][kc=c/8][n=p%64] ----------------
__global__ __launch_bounds__(256) void k_transp(const float* __restrict__ x,
                                                unsigned short* __restrict__ XTv) {
    __shared__ unsigned short lt[64][66];
    int ptile = blockIdx.x, ct = blockIdx.y;
    int t = threadIdx.x;
    int tx = t & 63, tw = t >> 6;
    int p0 = ptile * 64, c0 = ct * 64;
    #pragma unroll
    for (int i = 0; i < 16; ++i) {
        int row = tw * 16 + i;
        lt[row][tx] = f2bf(x[(size_t)(c0 + row) * HW + p0 + tx]);
    }
    __syncthreads();
    short8* dst = (short8*)XTv;
    #pragma unroll
    for (int ch = 0; ch < 2; ++ch) {
        int lc = ch * 256 + t;
        int kcg = lc >> 6, n = lc & 63;
        short8 v;
        #pragma unroll
        for (int e = 0; e < 8; ++e) v[e] = (short)lt[kcg * 8 + e][n];
        dst[ptile * 2048 + (ct * 8 + kcg) * 64 + n] = v;
    }
}

// ---------------- Kw: weights -> bf16 tiles [ot][kc][m] ----------------
__global__ __launch_bounds__(256) void k_wconv(const float* __restrict__ Wq,
                                               const float* __restrict__ Wv,
                                               short8* __restrict__ Wqt,
                                               short8* __restrict__ Wvt) {
    int cidx = blockIdx.x * 256 + threadIdx.x;          // 0..8191
    const float* src = blockIdx.y ? Wv : Wq;
    short8* dst = blockIdx.y ? Wvt : Wqt;
    int ot = cidx >> 11, kc = (cidx >> 6) & 31, m = cidx & 63;
    const float* s = src + (ot * 64 + m) * 256 + kc * 8;
    short8 v;
    #pragma unroll
    for (int e = 0; e < 8; ++e) v[e] = (short)f2bf(s[e]);
    dst[cidx] = v;
}

// ---------------- MFMA GEMM 64x64 tile, K=256 one-shot in LDS ----------------
template<int EPI>
__global__ __launch_bounds__(256) void k_gemm(const short8* __restrict__ Wt,
                                              const short8* __restrict__ Xt,
                                              const float* __restrict__ bias,
                                              unsigned* __restrict__ FQm,
                                              float* __restrict__ out) {
    __shared__ short8 As[2048];   // 32 KB  [kc][m]
    __shared__ short8 Bs[2048];   // 32 KB  [kc][n]
    int tid = threadIdx.x;
    int pt_ = blockIdx.x, ot = blockIdx.y;
    const short8* wsrc = Wt + ot * 2048;
    const short8* xsrc = Xt + pt_ * 2048;
    #pragma unroll
    for (int i = 0; i < 8; ++i) As[i * 256 + tid] = wsrc[i * 256 + tid];
    #pragma unroll
    for (int i = 0; i < 8; ++i) Bs[i * 256 + tid] = xsrc[i * 256 + tid];
    __syncthreads();

    int l = tid & 63, w = tid >> 6;
    int wr = w >> 1, wc = w & 1;
    int l15 = l & 15, quad = l >> 4;
    f32x4 acc[2][2] = {};
    int abase = wr * 32 + l15;
    int bbase = wc * 32 + l15;
    #pragma unroll
    for (int s = 0; s < 8; ++s) {
        int kc = s * 4 + quad;
        short8 a0 = As[kc * 64 + abase];
        short8 a1 = As[kc * 64 + abase + 16];
        short8 b0 = Bs[kc * 64 + bbase];
        short8 b1 = Bs[kc * 64 + bbase + 16];
        acc[0][0] = __builtin_amdgcn_mfma_f32_16x16x32_bf16(a0, b0, acc[0][0], 0, 0, 0);
        acc[0][1] = __builtin_amdgcn_mfma_f32_16x16x32_bf16(a0, b1, acc[0][1], 0, 0, 0);
        acc[1][0] = __builtin_amdgcn_mfma_f32_16x16x32_bf16(a1, b0, acc[1][0], 0, 0, 0);
        acc[1][1] = __builtin_amdgcn_mfma_f32_16x16x32_bf16(a1, b1, acc[1][1], 0, 0, 0);
    }

    // C/D layout: col = lane&15, row = quad*4 + reg
    if (EPI == 1) {
        #pragma unroll
        for (int ni = 0; ni < 2; ++ni) {
            #pragma unroll
            for (int r = 0; r < 4; ++r) {
                int o_lo = ot * 64 + wr * 32 + quad * 4 + r;
                float v = fmaxf(acc[0][ni][r] + bias[o_lo], acc[1][ni][r] + bias[o_lo + 16]);
                v = fmaxf(v, __shfl_xor(v, 32, 64));
                if (quad < 2) {
                    int p = pt_ * 64 + wc * 32 + ni * 16 + l15;
                    int k = ((quad * 4 + r) & 7) * HW + p;
                    if (k >= CW) k -= CW;
                    if (k >= CW) k -= CW;
                    unsigned u = __float_as_uint(v);
                    unsigned key = (u & 0x80000000u) ? ~u : (u | 0x80000000u);
                    atomicMax(&FQm[k], key);
                }
            }
        }
    } else {
        #pragma unroll
        for (int mi = 0; mi < 2; ++mi) {
            #pragma unroll
            for (int ni = 0; ni < 2; ++ni) {
                #pragma unroll
                for (int r = 0; r < 4; ++r) {
                    int o = ot * 64 + wr * 32 + mi * 16 + quad * 4 + r;
                    int p = pt_ * 64 + wc * 32 + ni * 16 + l15;
                    int k = ((quad * 4 + r) & 7) * HW + p;
                    if (k >= CW) k -= CW;
                    if (k >= CW) k -= CW;
                    unsigned key = FQm[k];
                    unsigned ub = (key & 0x80000000u) ? (key ^ 0x80000000u) : ~key;
                    float m = __uint_as_float(ub);
                    float v = acc[mi][ni][r] + bias[o];
                    out[(size_t)o * HW + p] = v * (1.0f + m);
                }
            }
        }
    }
}

extern "C" void kernel_launch(void* const* d_in, const int* in_sizes, int n_in,
                              void* d_out, int out_size, void* d_ws, size_t ws_size,
                              hipStream_t stream) {
    const float* fuse = (const float*)d_in[0];
    const float* Wq   = (const float*)d_in[1];
    const float* bq   = (const float*)d_in[2];
    // d_in[3]=Wk, d_in[4]=bk dead for B=1 (softmax over batch axis of size 1 == 1)
    const float* Wv   = (const float*)d_in[5];
    const float* bv   = (const float*)d_in[6];
    float* out = (float*)d_out;

    char* ws = (char*)d_ws;
    unsigned*       FQm  = (unsigned*)(ws);                  //  98304 B (24576 u32)
    unsigned*       MnMx = (unsigned*)(ws + 98304);          //   2048 B (512 u32)
    float*          Fg   = (float*)(ws + 100352);            //  32768 B
    short8*         Wqt  = (short8*)(ws + 133120);           // 131072 B
    short8*         Wvt  = (short8*)(ws + 264192);           // 131072 B
    unsigned short* XTq  = (unsigned short*)(ws + 395264);   // 4718592 B
    unsigned short* XTv  = (unsigned short*)(ws + 5113856);  // 4718592 B

    hipMemsetAsync(ws, 0, 100352, stream);   // FQm + MnMx
    k_minmax<<<2048, 256, 0, stream>>>(fuse, MnMx);
    k_wconv<<<dim3(32, 2), 256, 0, stream>>>(Wq, Wv, Wqt, Wvt);
    k_dft<<<256, 768, 0, stream>>>(fuse, MnMx, Fg);
    k_synth<<<dim3(96, 3), 256, 0, stream>>>(Fg, XTq);
    k_transp<<<dim3(144, 4), 256, 0, stream>>>(fuse, XTv);
    k_gemm<1><<<dim3(144, 4), 256, 0, stream>>>(Wqt, (const short8*)XTq, bq, FQm, nullptr);
    k_gemm<2><<<dim3(144, 4), 256, 0, stream>>>(Wvt, (const short8*)XTv, bv, FQm, out);
}